// Round 2
// baseline (611.563 us; speedup 1.0000x reference)
//
#include <hip/hip_runtime.h>
#include <math.h>

// Problem constants (B=1)
#define NTOK 4096
#define EMB  256
#define NH   4
#define HD   64

// ---------------------------------------------------------------------------
// Tiled fp32 GEMM: C[m][n] = sum_k A[m][k] * B[n][k] + bias[n] (+ resid[m][n])
// 64x64 block tile, K-step 32, 256 threads, 4x4 micro-tile per thread.
// LDS staged transposed: As/Bs indexed [k][m-or-n], stride 68 (16B-aligned,
// conflict-light). Inner loop: 2 ds_read_b128 per 16 v_fma.
// ---------------------------------------------------------------------------
__global__ __launch_bounds__(256) void gemm_abt(
    const float* __restrict__ A, int lda,
    const float* __restrict__ B,          // [Ncols][K]
    const float* __restrict__ bias,       // [Ncols]
    const float* __restrict__ resid, int ldr,  // may be null
    float* __restrict__ C, int ldc,
    int K)
{
    __shared__ float As[32 * 68];
    __shared__ float Bs[32 * 68];
    const int t  = threadIdx.x;
    const int tx = t & 15;        // col group
    const int ty = t >> 4;        // row group
    const int row0 = blockIdx.y * 64;
    const int col0 = blockIdx.x * 64;

    float acc[4][4] = {};

    const int r  = t >> 2;        // 0..63 (tile row/col to stage)
    const int cc = (t & 3) * 8;   // 0,8,16,24 (k offset)

    for (int k0 = 0; k0 < K; k0 += 32) {
        // load to regs first (hides latency across the barrier)
        const float* ap = A + (long)(row0 + r) * lda + k0 + cc;
        const float* bp = B + (long)(col0 + r) * K   + k0 + cc;
        float4 a0 = *(const float4*)(ap);
        float4 a1 = *(const float4*)(ap + 4);
        float4 b0 = *(const float4*)(bp);
        float4 b1 = *(const float4*)(bp + 4);

        __syncthreads();   // previous iteration's LDS reads done
        As[(cc + 0) * 68 + r] = a0.x; As[(cc + 1) * 68 + r] = a0.y;
        As[(cc + 2) * 68 + r] = a0.z; As[(cc + 3) * 68 + r] = a0.w;
        As[(cc + 4) * 68 + r] = a1.x; As[(cc + 5) * 68 + r] = a1.y;
        As[(cc + 6) * 68 + r] = a1.z; As[(cc + 7) * 68 + r] = a1.w;
        Bs[(cc + 0) * 68 + r] = b0.x; Bs[(cc + 1) * 68 + r] = b0.y;
        Bs[(cc + 2) * 68 + r] = b0.z; Bs[(cc + 3) * 68 + r] = b0.w;
        Bs[(cc + 4) * 68 + r] = b1.x; Bs[(cc + 5) * 68 + r] = b1.y;
        Bs[(cc + 6) * 68 + r] = b1.z; Bs[(cc + 7) * 68 + r] = b1.w;
        __syncthreads();

        #pragma unroll
        for (int kk = 0; kk < 32; ++kk) {
            float4 av4 = *(const float4*)(As + kk * 68 + ty * 4);
            float4 bv4 = *(const float4*)(Bs + kk * 68 + tx * 4);
            const float* av = (const float*)&av4;
            const float* bv = (const float*)&bv4;
            #pragma unroll
            for (int i = 0; i < 4; ++i)
                #pragma unroll
                for (int j = 0; j < 4; ++j)
                    acc[i][j] = fmaf(av[i], bv[j], acc[i][j]);
        }
    }

    const int colg = col0 + tx * 4;
    float4 bi4 = *(const float4*)(bias + colg);
    const float* bi = (const float*)&bi4;
    #pragma unroll
    for (int i = 0; i < 4; ++i) {
        const int row = row0 + ty * 4 + i;
        float4 o;
        float* op = (float*)&o;
        #pragma unroll
        for (int j = 0; j < 4; ++j) op[j] = acc[i][j] + bi[j];
        if (resid) {
            float4 rr = *(const float4*)(resid + (long)row * ldr + colg);
            const float* rp = (const float*)&rr;
            #pragma unroll
            for (int j = 0; j < 4; ++j) op[j] += rp[j];
        }
        *(float4*)(C + (long)row * ldc + colg) = o;
    }
}

// ---------------------------------------------------------------------------
// qkv (N,768) laid out per row as (h, d, 3) -> split into Q,K,V (H,N,D).
// RoPE applied to q,k: out[2i] = t[2i]*cos[2i] - t[2i+1]*sin[2i]
//                      out[2i+1] = t[2i+1]*cos[2i+1] + t[2i]*sin[2i+1]
// Softmax scale 1/sqrt(D) = 0.125 folded into Q.
// ---------------------------------------------------------------------------
__global__ __launch_bounds__(256) void rope_split(
    const float* __restrict__ qkv, const float* __restrict__ enc,
    float* __restrict__ Q, float* __restrict__ K, float* __restrict__ V)
{
    const int gid = blockIdx.x * 256 + threadIdx.x;   // NH*NTOK*32 total
    const int h   = gid >> 17;              // / (4096*32)
    const int rem = gid & (NTOK * 32 - 1);
    const int n   = rem >> 5;
    const int p   = rem & 31;
    const int d0  = p * 2;

    const float2* b2 = (const float2*)(qkv + (long)n * 768 + h * 192 + d0 * 3);
    float2 A  = b2[0];   // q0, k0
    float2 Bv = b2[1];   // v0, q1
    float2 C2 = b2[2];   // k1, v1
    float q0 = A.x, k0 = A.y, v0 = Bv.x, q1 = Bv.y, k1 = C2.x, v1 = C2.y;

    float2 c01 = *(const float2*)(enc + (long)n * 64 + d0);
    float2 s01 = *(const float2*)(enc + (long)NTOK * 64 + (long)n * 64 + d0);

    float qo0 = (q0 * c01.x - q1 * s01.x) * 0.125f;
    float qo1 = (q1 * c01.y + q0 * s01.y) * 0.125f;
    float ko0 = k0 * c01.x - k1 * s01.x;
    float ko1 = k1 * c01.y + k0 * s01.y;

    const long off = ((long)h * NTOK + n) * 64 + d0;
    *(float2*)(Q + off) = make_float2(qo0, qo1);
    *(float2*)(K + off) = make_float2(ko0, ko1);
    *(float2*)(V + off) = make_float2(v0, v1);
}

// copy x (N,256) into cat[:, 0:256] (row stride 512)
__global__ __launch_bounds__(256) void copy_x_cat(
    const float4* __restrict__ x4, float4* __restrict__ cat4)
{
    const int i = blockIdx.x * 256 + threadIdx.x;  // < 4096*64
    const int row = i >> 6, c = i & 63;
    cat4[(long)row * 128 + c] = x4[i];
}

// ---------------------------------------------------------------------------
// Flash attention fp32. One block per (q-tile of 64, head). 256 threads.
// LDS: Qs[64][64]; Kt[64][68] (d,ki) which is ALIASED by Ps[64][68] after the
// score phase (Kt dead once S is computed; barrier separates); Vt[64][68].
// thread (ty,tx): scores s[4][4] for q rows ty*4+i, k cols tx*4+j;
// online softmax reduced across the 16 tx lanes via shfl_xor;
// PV: output o[4][4] for d = tx+16*j (strided) from Ps/Vt.
// K/V staged with float4 global loads (coalesced 16B/lane), transposed
// scalar ds_writes into [d][ki] layout.
// ---------------------------------------------------------------------------
__global__ __launch_bounds__(256) void flash_attn(
    const float* __restrict__ Qg, const float* __restrict__ Kg,
    const float* __restrict__ Vg, float* __restrict__ ctx)
{
    __shared__ float sm[4096 + 2 * 64 * 68];   // 51200 B
    float* Qs = sm;                 // [64][64]
    float* Kt = sm + 4096;          // [64][68] (d, ki)
    float* Ps = Kt;                 // aliases Kt after scores
    float* Vt = Kt + 64 * 68;       // [64][68] (d, ki)

    const int t  = threadIdx.x;
    const int tx = t & 15, ty = t >> 4;
    const int h  = blockIdx.y;
    const int q0 = blockIdx.x * 64;

    const float* Qh = Qg + ((long)h * NTOK + q0) * 64;
    const float* Kh = Kg + (long)h * NTOK * 64;
    const float* Vh = Vg + (long)h * NTOK * 64;

    for (int idx = t; idx < 1024; idx += 256)
        *(float4*)(Qs + idx * 4) = *(const float4*)(Qh + idx * 4);

    float m[4], l[4], o[4][4];
    #pragma unroll
    for (int i = 0; i < 4; ++i) {
        m[i] = -1e30f; l[i] = 0.f;
        #pragma unroll
        for (int j = 0; j < 4; ++j) o[i][j] = 0.f;
    }

    for (int kt = 0; kt < NTOK; kt += 64) {
        // stage K/V tile: float4 loads (lane-coalesced), transposed stores.
        // load-to-reg BEFORE the barrier so the global latency overlaps the
        // previous tile's PV phase.
        float4 kreg[2], vreg[2];
        int kis[2], d4s[2];
        #pragma unroll
        for (int it = 0; it < 2; ++it) {
            const int idx = t + 256 * it;       // 0..511
            const int ki = idx >> 4;            // 0..31 / 32..63
            const int d4 = (idx & 15) * 4;
            kis[it] = ki; d4s[it] = d4;
            kreg[it] = *(const float4*)(Kh + (long)(kt + ki) * 64 + d4);
            vreg[it] = *(const float4*)(Vh + (long)(kt + ki) * 64 + d4);
        }
        __syncthreads();   // prev tile's PV reads done (and Qs staged, iter 0)
        #pragma unroll
        for (int it = 0; it < 2; ++it) {
            const int ki = kis[it], d4 = d4s[it];
            const float* kp = (const float*)&kreg[it];
            const float* vp = (const float*)&vreg[it];
            #pragma unroll
            for (int c = 0; c < 4; ++c) {
                Kt[(d4 + c) * 68 + ki] = kp[c];
                Vt[(d4 + c) * 68 + ki] = vp[c];
            }
        }
        __syncthreads();

        // ---- scores: s[i][j] = (Q*0.125) . K  over d=0..63 ----
        float s[4][4] = {};
        #pragma unroll
        for (int d4 = 0; d4 < 64; d4 += 4) {
            float4 qv[4], kv[4];
            #pragma unroll
            for (int i = 0; i < 4; ++i)
                qv[i] = *(const float4*)(Qs + (ty * 4 + i) * 64 + d4);
            #pragma unroll
            for (int c = 0; c < 4; ++c)
                kv[c] = *(const float4*)(Kt + (d4 + c) * 68 + tx * 4);
            #pragma unroll
            for (int i = 0; i < 4; ++i) {
                const float* q = (const float*)&qv[i];
                #pragma unroll
                for (int c = 0; c < 4; ++c) {
                    const float* k = (const float*)&kv[c];
                    #pragma unroll
                    for (int j = 0; j < 4; ++j)
                        s[i][j] = fmaf(q[c], k[j], s[i][j]);
                }
            }
        }
        __syncthreads();   // everyone done reading Kt; Ps may overwrite it

        // ---- online softmax; write P tile ----
        #pragma unroll
        for (int i = 0; i < 4; ++i) {
            float mx = fmaxf(fmaxf(s[i][0], s[i][1]), fmaxf(s[i][2], s[i][3]));
            #pragma unroll
            for (int w = 1; w < 16; w <<= 1) mx = fmaxf(mx, __shfl_xor(mx, w));
            const float mn   = fmaxf(m[i], mx);
            const float corr = __expf(m[i] - mn);
            float4 p4;
            float* pp = (float*)&p4;
            float ps = 0.f;
            #pragma unroll
            for (int j = 0; j < 4; ++j) { pp[j] = __expf(s[i][j] - mn); ps += pp[j]; }
            #pragma unroll
            for (int w = 1; w < 16; w <<= 1) ps += __shfl_xor(ps, w);
            l[i] = l[i] * corr + ps;
            m[i] = mn;
            #pragma unroll
            for (int j = 0; j < 4; ++j) o[i][j] *= corr;
            *(float4*)(Ps + (ty * 4 + i) * 68 + tx * 4) = p4;
        }
        // P rows are written and read by the SAME 16-lane group of one wave;
        // per-wave LDS ops complete in order -> no barrier needed here.

        // ---- PV: o[i][j] += P[qi][ki] * V[ki][d], d = tx+16j ----
        #pragma unroll
        for (int k4 = 0; k4 < 64; k4 += 4) {
            float4 pv[4], vv[4];
            #pragma unroll
            for (int i = 0; i < 4; ++i)
                pv[i] = *(const float4*)(Ps + (ty * 4 + i) * 68 + k4);
            #pragma unroll
            for (int j = 0; j < 4; ++j)
                vv[j] = *(const float4*)(Vt + (tx + 16 * j) * 68 + k4);
            #pragma unroll
            for (int i = 0; i < 4; ++i) {
                const float* p = (const float*)&pv[i];
                #pragma unroll
                for (int j = 0; j < 4; ++j) {
                    const float* v = (const float*)&vv[j];
                    #pragma unroll
                    for (int c = 0; c < 4; ++c)
                        o[i][j] = fmaf(p[c], v[c], o[i][j]);
                }
            }
        }
    }

    // epilogue: ctx[n][h*64 + d] = o / l   (ctx layout (N, E))
    #pragma unroll
    for (int i = 0; i < 4; ++i) {
        const float rl = 1.f / l[i];
        const int row = q0 + ty * 4 + i;
        #pragma unroll
        for (int j = 0; j < 4; ++j)
            ctx[(long)row * EMB + h * 64 + tx + 16 * j] = o[i][j] * rl;
    }
}

// ---------------------------------------------------------------------------
// Row LayerNorm(512) + exact GeLU. One block (256 thr) per row, 2 elems/thr.
// ---------------------------------------------------------------------------
__global__ __launch_bounds__(256) void ln_gelu(
    const float* __restrict__ h1, const float* __restrict__ g,
    const float* __restrict__ b, float* __restrict__ h2)
{
    __shared__ float red[8];
    const int row = blockIdx.x, t = threadIdx.x;
    const float v0 = h1[(long)row * 512 + t];
    const float v1 = h1[(long)row * 512 + 256 + t];

    float s = v0 + v1;
    #pragma unroll
    for (int w = 1; w < 64; w <<= 1) s += __shfl_xor(s, w);
    if ((t & 63) == 0) red[t >> 6] = s;
    __syncthreads();
    const float mu = (red[0] + red[1] + red[2] + red[3]) * (1.f / 512.f);

    const float d0 = v0 - mu, d1 = v1 - mu;
    float vs = d0 * d0 + d1 * d1;
    #pragma unroll
    for (int w = 1; w < 64; w <<= 1) vs += __shfl_xor(vs, w);
    if ((t & 63) == 0) red[4 + (t >> 6)] = vs;
    __syncthreads();
    const float var  = (red[4] + red[5] + red[6] + red[7]) * (1.f / 512.f);
    const float rstd = rsqrtf(var + 1e-5f);

    const float y0 = d0 * rstd * g[t] + b[t];
    const float y1 = d1 * rstd * g[t + 256] + b[t + 256];
    const float o0 = 0.5f * y0 * (1.f + erff(y0 * 0.70710678118654752f));
    const float o1 = 0.5f * y1 * (1.f + erff(y1 * 0.70710678118654752f));
    h2[(long)row * 512 + t] = o0;
    h2[(long)row * 512 + 256 + t] = o1;
}

// ---------------------------------------------------------------------------
extern "C" void kernel_launch(void* const* d_in, const int* in_sizes, int n_in,
                              void* d_out, int out_size, void* d_ws, size_t ws_size,
                              hipStream_t stream)
{
    const float* x      = (const float*)d_in[0];
    const float* enc    = (const float*)d_in[1];
    const float* Wqkv_w = (const float*)d_in[2];
    const float* Wqkv_b = (const float*)d_in[3];
    const float* out_w  = (const float*)d_in[4];
    const float* out_b  = (const float*)d_in[5];
    const float* ffn1_w = (const float*)d_in[6];
    const float* ffn1_b = (const float*)d_in[7];
    const float* ln_g   = (const float*)d_in[8];
    const float* ln_b   = (const float*)d_in[9];
    const float* ffn2_w = (const float*)d_in[10];
    const float* ffn2_b = (const float*)d_in[11];
    float* out = (float*)d_out;
    float* ws  = (float*)d_ws;

    // workspace layout (floats); peak ~7.34M floats = 29.4 MB
    float* qkv = ws;                    // 4096*768
    float* Q   = ws + 3145728;          // H*N*D
    float* K   = Q + 1048576;
    float* V   = K + 1048576;
    float* ctx = V + 1048576;           // 4096*256
    float* cat = qkv;                   // reuse (qkv dead after rope_split)
    float* h1  = Q;                     // reuse (spans Q,K; dead after flash)
    float* h2  = V;                     // reuse (spans V,ctx)

    // 1. QKV projection: (4096,256) @ (768,256)^T
    gemm_abt<<<dim3(12, 64), 256, 0, stream>>>(x, 256, Wqkv_w, Wqkv_b,
                                               nullptr, 0, qkv, 768, 256);
    // 2. RoPE + split to (H,N,D), scale folded into Q
    rope_split<<<2048, 256, 0, stream>>>(qkv, enc, Q, K, V);
    // 3. x -> cat[:, :256]   (must run after rope_split: cat aliases qkv)
    copy_x_cat<<<1024, 256, 0, stream>>>((const float4*)x, (float4*)cat);
    // 4. attention -> ctx (N, E)
    flash_attn<<<dim3(64, NH), 256, 0, stream>>>(Q, K, V, ctx);
    // 5. out_proj -> cat[:, 256:]
    gemm_abt<<<dim3(4, 64), 256, 0, stream>>>(ctx, 256, out_w, out_b,
                                              nullptr, 0, cat + 256, 512, 256);
    // 6. FFN1: (4096,512) @ (512,512)^T
    gemm_abt<<<dim3(8, 64), 256, 0, stream>>>(cat, 512, ffn1_w, ffn1_b,
                                              nullptr, 0, h1, 512, 512);
    // 7. LayerNorm + exact GeLU
    ln_gelu<<<4096, 256, 0, stream>>>(h1, ln_g, ln_b, h2);
    // 8. FFN2 + residual: out = x + h2 @ (256,512)^T
    gemm_abt<<<dim3(4, 64), 256, 0, stream>>>(h2, 512, ffn2_w, ffn2_b,
                                              x, 256, out, 256, 512);
}

// Round 3
// 288.511 us; speedup vs baseline: 2.1197x; 2.1197x over previous
//
#include <hip/hip_runtime.h>
#include <math.h>

// Problem constants (B=1)
#define NTOK 4096
#define EMB  256
#define NH   4
#define HD   64

typedef unsigned short u16;
typedef __attribute__((ext_vector_type(8))) __bf16 bf16x8;
typedef __attribute__((ext_vector_type(4))) float f32x4;

__device__ __forceinline__ u16 f2bf(float f) {
    union { float f; unsigned u; } v; v.f = f;
    unsigned b = v.u;
    b += 0x7FFFu + ((b >> 16) & 1u);     // round-nearest-even
    return (u16)(b >> 16);
}

// ---------------------------------------------------------------------------
// Tiled fp32 GEMM: C[m][n] = sum_k A[m][k] * B[n][k] + bias[n] (+ resid[m][n])
// (unchanged from round 2 — verified working)
// ---------------------------------------------------------------------------
__global__ __launch_bounds__(256) void gemm_abt(
    const float* __restrict__ A, int lda,
    const float* __restrict__ B,          // [Ncols][K]
    const float* __restrict__ bias,       // [Ncols]
    const float* __restrict__ resid, int ldr,  // may be null
    float* __restrict__ C, int ldc,
    int K)
{
    __shared__ float As[32 * 68];
    __shared__ float Bs[32 * 68];
    const int t  = threadIdx.x;
    const int tx = t & 15;
    const int ty = t >> 4;
    const int row0 = blockIdx.y * 64;
    const int col0 = blockIdx.x * 64;

    float acc[4][4] = {};

    const int r  = t >> 2;
    const int cc = (t & 3) * 8;

    for (int k0 = 0; k0 < K; k0 += 32) {
        const float* ap = A + (long)(row0 + r) * lda + k0 + cc;
        const float* bp = B + (long)(col0 + r) * K   + k0 + cc;
        float4 a0 = *(const float4*)(ap);
        float4 a1 = *(const float4*)(ap + 4);
        float4 b0 = *(const float4*)(bp);
        float4 b1 = *(const float4*)(bp + 4);

        __syncthreads();
        As[(cc + 0) * 68 + r] = a0.x; As[(cc + 1) * 68 + r] = a0.y;
        As[(cc + 2) * 68 + r] = a0.z; As[(cc + 3) * 68 + r] = a0.w;
        As[(cc + 4) * 68 + r] = a1.x; As[(cc + 5) * 68 + r] = a1.y;
        As[(cc + 6) * 68 + r] = a1.z; As[(cc + 7) * 68 + r] = a1.w;
        Bs[(cc + 0) * 68 + r] = b0.x; Bs[(cc + 1) * 68 + r] = b0.y;
        Bs[(cc + 2) * 68 + r] = b0.z; Bs[(cc + 3) * 68 + r] = b0.w;
        Bs[(cc + 4) * 68 + r] = b1.x; Bs[(cc + 5) * 68 + r] = b1.y;
        Bs[(cc + 6) * 68 + r] = b1.z; Bs[(cc + 7) * 68 + r] = b1.w;
        __syncthreads();

        #pragma unroll
        for (int kk = 0; kk < 32; ++kk) {
            float4 av4 = *(const float4*)(As + kk * 68 + ty * 4);
            float4 bv4 = *(const float4*)(Bs + kk * 68 + tx * 4);
            const float* av = (const float*)&av4;
            const float* bv = (const float*)&bv4;
            #pragma unroll
            for (int i = 0; i < 4; ++i)
                #pragma unroll
                for (int j = 0; j < 4; ++j)
                    acc[i][j] = fmaf(av[i], bv[j], acc[i][j]);
        }
    }

    const int colg = col0 + tx * 4;
    float4 bi4 = *(const float4*)(bias + colg);
    const float* bi = (const float*)&bi4;
    #pragma unroll
    for (int i = 0; i < 4; ++i) {
        const int row = row0 + ty * 4 + i;
        float4 o;
        float* op = (float*)&o;
        #pragma unroll
        for (int j = 0; j < 4; ++j) op[j] = acc[i][j] + bi[j];
        if (resid) {
            float4 rr = *(const float4*)(resid + (long)row * ldr + colg);
            const float* rp = (const float*)&rr;
            #pragma unroll
            for (int j = 0; j < 4; ++j) op[j] += rp[j];
        }
        *(float4*)(C + (long)row * ldc + colg) = o;
    }
}

// ---------------------------------------------------------------------------
// RoPE -> bf16 Q (scale 0.125 folded) and bf16 K, layout [h][n][64].
// qkv row layout per (n): h*192 + d*3 + {0:q,1:k,2:v}.
// ---------------------------------------------------------------------------
__global__ __launch_bounds__(256) void rope_qk(
    const float* __restrict__ qkv, const float* __restrict__ enc,
    unsigned* __restrict__ Qb, unsigned* __restrict__ Kb)
{
    const int gid = blockIdx.x * 256 + threadIdx.x;   // NH*NTOK*32
    const int h   = gid >> 17;
    const int rem = gid & (NTOK * 32 - 1);
    const int n   = rem >> 5;
    const int p   = rem & 31;
    const int d0  = p * 2;

    const float2* b2 = (const float2*)(qkv + (size_t)n * 768 + h * 192 + d0 * 3);
    float2 A  = b2[0];   // q0, k0
    float2 Bv = b2[1];   // v0, q1
    float2 C2 = b2[2];   // k1, v1
    const float q0v = A.x, k0 = A.y, q1 = Bv.y, k1 = C2.x;

    float2 c01 = *(const float2*)(enc + (size_t)n * 64 + d0);
    float2 s01 = *(const float2*)(enc + (size_t)NTOK * 64 + (size_t)n * 64 + d0);

    const float qo0 = (q0v * c01.x - q1 * s01.x) * 0.125f;
    const float qo1 = (q1 * c01.y + q0v * s01.y) * 0.125f;
    const float ko0 = k0 * c01.x - k1 * s01.x;
    const float ko1 = k1 * c01.y + k0 * s01.y;

    const size_t oidx = ((size_t)(h * NTOK + n) << 5) + p;  // uint (2-elem) index
    Qb[oidx] = (unsigned)f2bf(qo0) | ((unsigned)f2bf(qo1) << 16);
    Kb[oidx] = (unsigned)f2bf(ko0) | ((unsigned)f2bf(ko1) << 16);
}

// ---------------------------------------------------------------------------
// V -> bf16 transposed: Vt[h][d][key], read straight from qkv (v slot).
// One block per (h, 64-token tile); thread (d = t&63, nc = t>>6) handles 16
// consecutive tokens for one d -> 32B coalesced store.
// ---------------------------------------------------------------------------
__global__ __launch_bounds__(256) void v_transpose(
    const float* __restrict__ qkv, u16* __restrict__ Vt)
{
    const int h  = blockIdx.x >> 6;
    const int nt = blockIdx.x & 63;
    const int t  = threadIdx.x;
    const int d  = t & 63;
    const int nc = t >> 6;   // 0..3

    __align__(16) u16 us[16];
    #pragma unroll
    for (int i = 0; i < 16; ++i) {
        const int n = nt * 64 + nc * 16 + i;
        us[i] = f2bf(qkv[(size_t)n * 768 + h * 192 + d * 3 + 2]);
    }
    u16* dst = Vt + ((size_t)(h * 64 + d) << 12) + nt * 64 + nc * 16;
    *(uint4*)(dst)     = *(uint4*)(us);
    *(uint4*)(dst + 8) = *(uint4*)(us + 8);
}

// copy x (N,256) into cat[:, 0:256] (row stride 512)
__global__ __launch_bounds__(256) void copy_x_cat(
    const float4* __restrict__ x4, float4* __restrict__ cat4)
{
    const int i = blockIdx.x * 256 + threadIdx.x;  // < 4096*64
    const int row = i >> 6, c = i & 63;
    cat4[(long)row * 128 + c] = x4[i];
}

// ---------------------------------------------------------------------------
// Flash attention, bf16 MFMA (16x16x32), fp32 accum.
// Block = (64 q-rows, head), 4 waves. Wave w owns keys [w*1024, w*1024+1024),
// ALL 64 q-rows (key-split: K/V read exactly once per block, no barriers in
// the main loop; waves fully independent until the final merge).
// Fragments (guide §3, m89/m91-verified):
//   A[row=l&15][k=(l>>4)*8+j], B[col=l&15][k=(l>>4)*8+j],
//   C/D[row=(l>>4)*4+reg][col=l&15].
// P goes through a per-wave private LDS tile (8KB) with 16B-slot XOR swizzle
// (slot ^= row&7) so A-fragment b128 reads hit the 8-cycle floor.
// Cross-wave online-softmax merge via a 16KB LDS buffer, wave-serialized.
// ---------------------------------------------------------------------------
__global__ __launch_bounds__(256, 1) void flash_attn_mfma(
    const u16* __restrict__ Qb, const u16* __restrict__ Kb,
    const u16* __restrict__ Vt, float* __restrict__ ctx)
{
    __shared__ char  Plds[4 * 8192];
    __shared__ float Obuf[64 * 64];
    __shared__ float Mbuf[64], Lbuf[64];

    const int t  = threadIdx.x;
    const int w  = t >> 6;
    const int l  = t & 63;
    const int lg = l >> 4, li = l & 15;
    const int h  = blockIdx.y;
    const int q0 = blockIdx.x * 64;

    char* Pw = Plds + w * 8192;

    // Q fragments (persist whole kernel): rows q0+Mb*16+li, d = kh*32+lg*8+{0..7}
    bf16x8 QA[4][2];
    #pragma unroll
    for (int Mb = 0; Mb < 4; ++Mb)
        #pragma unroll
        for (int kh = 0; kh < 2; ++kh)
            QA[Mb][kh] = *(const bf16x8*)(Qb +
                ((size_t)(h * NTOK + q0 + Mb * 16 + li) << 6) + kh * 32 + lg * 8);

    f32x4 OA[4][4];           // [Mb][db]
    float mrun[4][4], lrun[4][4];   // [Mb][p]
    #pragma unroll
    for (int Mb = 0; Mb < 4; ++Mb) {
        #pragma unroll
        for (int p = 0; p < 4; ++p) { mrun[Mb][p] = -1e30f; lrun[Mb][p] = 0.f; }
        #pragma unroll
        for (int db = 0; db < 4; ++db) OA[Mb][db] = (f32x4){0.f, 0.f, 0.f, 0.f};
    }

    for (int it = 0; it < 16; ++it) {
        const int kt = (w << 10) + (it << 6);

        // ---- issue all K/V fragment loads for this tile ----
        bf16x8 KB[4][2], VB[4][2];
        #pragma unroll
        for (int kb = 0; kb < 4; ++kb)
            #pragma unroll
            for (int kh = 0; kh < 2; ++kh)
                KB[kb][kh] = *(const bf16x8*)(Kb +
                    ((size_t)(h * NTOK + kt + kb * 16 + li) << 6) + kh * 32 + lg * 8);
        #pragma unroll
        for (int db = 0; db < 4; ++db)
            #pragma unroll
            for (int kh = 0; kh < 2; ++kh)
                VB[db][kh] = *(const bf16x8*)(Vt +
                    ((size_t)(h * 64 + db * 16 + li) << 12) + kt + kh * 32 + lg * 8);

        // ---- scores: S[q][key], 16x16 tiles, K=64 as 2 chained mfmas ----
        f32x4 SA[4][4];
        #pragma unroll
        for (int Mb = 0; Mb < 4; ++Mb)
            #pragma unroll
            for (int kb = 0; kb < 4; ++kb) {
                f32x4 z = (f32x4){0.f, 0.f, 0.f, 0.f};
                z = __builtin_amdgcn_mfma_f32_16x16x32_bf16(QA[Mb][0], KB[kb][0], z, 0, 0, 0);
                SA[Mb][kb] = __builtin_amdgcn_mfma_f32_16x16x32_bf16(QA[Mb][1], KB[kb][1], z, 0, 0, 0);
            }

        // ---- online softmax (rows live in (lg,p); reduce over 16 li lanes) ----
        #pragma unroll
        for (int Mb = 0; Mb < 4; ++Mb)
            #pragma unroll
            for (int p = 0; p < 4; ++p) {
                float mx = fmaxf(fmaxf(SA[Mb][0][p], SA[Mb][1][p]),
                                 fmaxf(SA[Mb][2][p], SA[Mb][3][p]));
                #pragma unroll
                for (int sh = 1; sh < 16; sh <<= 1)
                    mx = fmaxf(mx, __shfl_xor(mx, sh));
                const float mo = mrun[Mb][p];
                const float mn = fmaxf(mo, mx);
                const float corr = __expf(mo - mn);
                mrun[Mb][p] = mn;
                float pv[4], ps = 0.f;
                #pragma unroll
                for (int kb = 0; kb < 4; ++kb) {
                    pv[kb] = __expf(SA[Mb][kb][p] - mn);
                    ps += pv[kb];
                }
                #pragma unroll
                for (int sh = 1; sh < 16; sh <<= 1) ps += __shfl_xor(ps, sh);
                lrun[Mb][p] = lrun[Mb][p] * corr + ps;
                #pragma unroll
                for (int db = 0; db < 4; ++db) OA[Mb][db][p] *= corr;

                const int ql = Mb * 16 + lg * 4 + p;
                #pragma unroll
                for (int kb = 0; kb < 4; ++kb) {
                    const int kl = kb * 16 + li;
                    *(u16*)(Pw + ql * 128 + ((kl * 2) ^ ((ql & 7) << 4))) = f2bf(pv[kb]);
                }
            }

        // ---- PV: ctx[q][d] += P[q][key] * V[key][d] ----
        // (per-wave DS pipe is in-order: P writes above complete before reads)
        #pragma unroll
        for (int Mb = 0; Mb < 4; ++Mb)
            #pragma unroll
            for (int kh = 0; kh < 2; ++kh) {
                const int ql = Mb * 16 + li;
                bf16x8 PA = *(const bf16x8*)(Pw + ql * 128 +
                                ((kh * 64 + lg * 16) ^ ((ql & 7) << 4)));
                #pragma unroll
                for (int db = 0; db < 4; ++db)
                    OA[Mb][db] = __builtin_amdgcn_mfma_f32_16x16x32_bf16(
                        PA, VB[db][kh], OA[Mb][db], 0, 0, 0);
            }
    }

    // ---- cross-wave online-softmax merge (wave-serialized through LDS) ----
    if (w == 0) {
        #pragma unroll
        for (int Mb = 0; Mb < 4; ++Mb)
            #pragma unroll
            for (int p = 0; p < 4; ++p) {
                const int q = Mb * 16 + lg * 4 + p;
                #pragma unroll
                for (int db = 0; db < 4; ++db)
                    Obuf[q * 64 + db * 16 + li] = OA[Mb][db][p];
                if (li == 0) { Mbuf[q] = mrun[Mb][p]; Lbuf[q] = lrun[Mb][p]; }
            }
    }
    #pragma unroll
    for (int wv = 1; wv < 4; ++wv) {
        __syncthreads();
        if (w == wv) {
            #pragma unroll
            for (int Mb = 0; Mb < 4; ++Mb)
                #pragma unroll
                for (int p = 0; p < 4; ++p) {
                    const int q = Mb * 16 + lg * 4 + p;
                    const float Mo = Mbuf[q], Lo = Lbuf[q];
                    const float mn = fmaxf(Mo, mrun[Mb][p]);
                    const float a  = __expf(Mo - mn);
                    const float b  = __expf(mrun[Mb][p] - mn);
                    #pragma unroll
                    for (int db = 0; db < 4; ++db) {
                        const int idx = q * 64 + db * 16 + li;
                        Obuf[idx] = Obuf[idx] * a + OA[Mb][db][p] * b;
                    }
                    if (li == 0) { Mbuf[q] = mn; Lbuf[q] = Lo * a + lrun[Mb][p] * b; }
                }
        }
    }
    __syncthreads();

    // ---- write ctx (N, E): ctx[q0+q][h*64 + d] = Obuf/L ----
    {
        const int q = t >> 2, dc = (t & 3) * 16;
        const float rl = 1.f / Lbuf[q];
        #pragma unroll
        for (int i = 0; i < 16; i += 4) {
            float4 o;
            o.x = Obuf[q * 64 + dc + i + 0] * rl;
            o.y = Obuf[q * 64 + dc + i + 1] * rl;
            o.z = Obuf[q * 64 + dc + i + 2] * rl;
            o.w = Obuf[q * 64 + dc + i + 3] * rl;
            *(float4*)(ctx + (size_t)(q0 + q) * EMB + h * 64 + dc + i) = o;
        }
    }
}

// ---------------------------------------------------------------------------
// Row LayerNorm(512) + exact GeLU (unchanged).
// ---------------------------------------------------------------------------
__global__ __launch_bounds__(256) void ln_gelu(
    const float* __restrict__ h1, const float* __restrict__ g,
    const float* __restrict__ b, float* __restrict__ h2)
{
    __shared__ float red[8];
    const int row = blockIdx.x, t = threadIdx.x;
    const float v0 = h1[(long)row * 512 + t];
    const float v1 = h1[(long)row * 512 + 256 + t];

    float s = v0 + v1;
    #pragma unroll
    for (int w = 1; w < 64; w <<= 1) s += __shfl_xor(s, w);
    if ((t & 63) == 0) red[t >> 6] = s;
    __syncthreads();
    const float mu = (red[0] + red[1] + red[2] + red[3]) * (1.f / 512.f);

    const float d0 = v0 - mu, d1 = v1 - mu;
    float vs = d0 * d0 + d1 * d1;
    #pragma unroll
    for (int w = 1; w < 64; w <<= 1) vs += __shfl_xor(vs, w);
    if ((t & 63) == 0) red[4 + (t >> 6)] = vs;
    __syncthreads();
    const float var  = (red[4] + red[5] + red[6] + red[7]) * (1.f / 512.f);
    const float rstd = rsqrtf(var + 1e-5f);

    const float y0 = d0 * rstd * g[t] + b[t];
    const float y1 = d1 * rstd * g[t + 256] + b[t + 256];
    const float o0 = 0.5f * y0 * (1.f + erff(y0 * 0.70710678118654752f));
    const float o1 = 0.5f * y1 * (1.f + erff(y1 * 0.70710678118654752f));
    h2[(long)row * 512 + t] = o0;
    h2[(long)row * 512 + 256 + t] = o1;
}

// ---------------------------------------------------------------------------
extern "C" void kernel_launch(void* const* d_in, const int* in_sizes, int n_in,
                              void* d_out, int out_size, void* d_ws, size_t ws_size,
                              hipStream_t stream)
{
    const float* x      = (const float*)d_in[0];
    const float* enc    = (const float*)d_in[1];
    const float* Wqkv_w = (const float*)d_in[2];
    const float* Wqkv_b = (const float*)d_in[3];
    const float* out_w  = (const float*)d_in[4];
    const float* out_b  = (const float*)d_in[5];
    const float* ffn1_w = (const float*)d_in[6];
    const float* ffn1_b = (const float*)d_in[7];
    const float* ln_g   = (const float*)d_in[8];
    const float* ln_b   = (const float*)d_in[9];
    const float* ffn2_w = (const float*)d_in[10];
    const float* ffn2_b = (const float*)d_in[11];
    float* out = (float*)d_out;
    float* ws  = (float*)d_ws;

    // workspace layout (float units), peak 5.77M floats = 23.1 MB:
    //  [0)         qkv fp32 4096x768            (3,145,728)   } cat/h2 alias
    //  [3145728)   Qb  bf16 4x4096x64           (524,288 f)   }
    //  [3670016)   Kb  bf16 4x4096x64           (524,288 f)   } h1 aliases
    //  [4194304)   Vt  bf16 4x64x4096           (524,288 f)   } Qb..ctx
    //  [4718592)   ctx fp32 4096x256            (1,048,576)   }
    float* qkv = ws;
    u16*   Qb  = (u16*)(ws + 3145728);
    u16*   Kb  = (u16*)(ws + 3670016);
    u16*   Vt  = (u16*)(ws + 4194304);
    float* ctx = ws + 4718592;
    float* cat = qkv;            // qkv dead after rope_qk + v_transpose
    float* h1  = ws + 3145728;   // Qb/Kb/Vt/ctx dead after out_proj
    float* h2  = ws;             // cat dead after FFN1

    // 1. QKV projection (fp32): (4096,256) @ (768,256)^T
    gemm_abt<<<dim3(12, 64), 256, 0, stream>>>(x, 256, Wqkv_w, Wqkv_b,
                                               nullptr, 0, qkv, 768, 256);
    // 2. RoPE -> bf16 Q (x0.125), K
    rope_qk<<<2048, 256, 0, stream>>>(qkv, enc, (unsigned*)Qb, (unsigned*)Kb);
    // 3. V -> bf16 transposed [h][d][key]
    v_transpose<<<256, 256, 0, stream>>>(qkv, Vt);
    // 4. x -> cat[:, :256]  (after v_transpose: cat aliases qkv)
    copy_x_cat<<<1024, 256, 0, stream>>>((const float4*)x, (float4*)cat);
    // 5. attention (bf16 MFMA) -> ctx (N, E)
    flash_attn_mfma<<<dim3(64, NH), 256, 0, stream>>>(Qb, Kb, Vt, ctx);
    // 6. out_proj (fp32) -> cat[:, 256:]
    gemm_abt<<<dim3(4, 64), 256, 0, stream>>>(ctx, 256, out_w, out_b,
                                              nullptr, 0, cat + 256, 512, 256);
    // 7. FFN1 (fp32): (4096,512) @ (512,512)^T
    gemm_abt<<<dim3(8, 64), 256, 0, stream>>>(cat, 512, ffn1_w, ffn1_b,
                                              nullptr, 0, h1, 512, 512);
    // 8. LayerNorm + exact GeLU
    ln_gelu<<<4096, 256, 0, stream>>>(h1, ln_g, ln_b, h2);
    // 9. FFN2 + residual: out = x + h2 @ (256,512)^T
    gemm_abt<<<dim3(4, 64), 256, 0, stream>>>(h2, 512, ffn2_w, ffn2_b,
                                              x, 256, out, 256, 512);
}

// Round 4
// 229.890 us; speedup vs baseline: 2.6602x; 1.2550x over previous
//
#include <hip/hip_runtime.h>
#include <math.h>

// Problem constants (B=1)
#define NTOK 4096
#define EMB  256
#define NH   4
#define HD   64

typedef unsigned short u16;
typedef __attribute__((ext_vector_type(8))) __bf16 bf16x8;
typedef __attribute__((ext_vector_type(4))) float f32x4;

__device__ __forceinline__ u16 f2bf(float f) {
    union { float f; unsigned u; } v; v.f = f;
    unsigned b = v.u;
    b += 0x7FFFu + ((b >> 16) & 1u);     // round-nearest-even
    return (u16)(b >> 16);
}
__device__ __forceinline__ float bf2f(u16 u) {
    union { unsigned u; float f; } v; v.u = ((unsigned)u) << 16;
    return v.f;
}

// ---------------------------------------------------------------------------
// Weight cast: 4 fp32 weight tensors -> one concatenated bf16 buffer.
// Segments (float4 units): Wqkv 49152 | out_w 16384 | ffn1 65536 | ffn2 32768
// ---------------------------------------------------------------------------
__global__ __launch_bounds__(256) void w4cast(
    const float4* __restrict__ w0, const float4* __restrict__ w1,
    const float4* __restrict__ w2, const float4* __restrict__ w3,
    u16* __restrict__ dst)
{
    const int f = blockIdx.x * 256 + threadIdx.x;   // < 163840
    float4 v;
    if      (f <  49152) v = w0[f];
    else if (f <  65536) v = w1[f - 49152];
    else if (f < 131072) v = w2[f - 65536];
    else                 v = w3[f - 131072];
    uint2 o;
    o.x = (unsigned)f2bf(v.x) | ((unsigned)f2bf(v.y) << 16);
    o.y = (unsigned)f2bf(v.z) | ((unsigned)f2bf(v.w) << 16);
    *(uint2*)(dst + (size_t)f * 4) = o;
}

// x fp32 (4096,256) -> xb bf16 (contiguous) AND catb[:, :256] (row stride 512)
__global__ __launch_bounds__(256) void xcast(
    const float4* __restrict__ x4, u16* __restrict__ xb, u16* __restrict__ catb)
{
    const int f = blockIdx.x * 256 + threadIdx.x;   // < 262144
    float4 v = x4[f];
    uint2 o;
    o.x = (unsigned)f2bf(v.x) | ((unsigned)f2bf(v.y) << 16);
    o.y = (unsigned)f2bf(v.z) | ((unsigned)f2bf(v.w) << 16);
    *(uint2*)(xb + (size_t)f * 4) = o;
    const int row = f >> 6, c = (f & 63) * 4;
    *(uint2*)(catb + (size_t)row * 512 + c) = o;
}

// ---------------------------------------------------------------------------
// bf16 MFMA GEMM: C[m][n] = sum_k A[m][k]*B[n][k] + bias[n] (+resid) .
// Block 256 thr / 4 waves; tile 64(M)x64(N); wave w owns rows w*16..+15.
// Fragments (HW-verified in round-3 flash kernel):
//   A[row=li][k=lg*8+j], B[col=li][k=lg*8+j], D[row=lg*4+p][col=li].
// No LDS: A/B fragments straight from global (L1/L2-resident at these sizes).
// Output fp32 (Cf) or bf16 (Cb) — exactly one non-null.
// ---------------------------------------------------------------------------
__global__ __launch_bounds__(256) void gemm_bf16_abt(
    const u16* __restrict__ A,     // [M][K] bf16
    const u16* __restrict__ B,     // [N][K] bf16
    const float* __restrict__ bias,
    const float* __restrict__ resid, int ldr,   // may be null
    float* __restrict__ Cf, u16* __restrict__ Cb, int ldc, int K)
{
    const int t = threadIdx.x, w = t >> 6, l = t & 63;
    const int lg = l >> 4, li = l & 15;
    const int row0 = blockIdx.y * 64 + w * 16;
    const int col0 = blockIdx.x * 64;

    f32x4 acc[4];
    #pragma unroll
    for (int nb = 0; nb < 4; ++nb) acc[nb] = (f32x4){0.f, 0.f, 0.f, 0.f};

    const u16* Ap = A + (size_t)(row0 + li) * K + lg * 8;
    const u16* Bp = B + (size_t)(col0 + li) * K + lg * 8;

    #pragma unroll 2
    for (int k0 = 0; k0 < K; k0 += 32) {
        bf16x8 a = *(const bf16x8*)(Ap + k0);
        #pragma unroll
        for (int nb = 0; nb < 4; ++nb) {
            bf16x8 b = *(const bf16x8*)(Bp + (size_t)nb * 16 * K + k0);
            acc[nb] = __builtin_amdgcn_mfma_f32_16x16x32_bf16(a, b, acc[nb], 0, 0, 0);
        }
    }

    #pragma unroll
    for (int nb = 0; nb < 4; ++nb) {
        const int col = col0 + nb * 16 + li;
        const float bs = bias[col];
        #pragma unroll
        for (int p = 0; p < 4; ++p) {
            const int row = row0 + lg * 4 + p;
            float v = acc[nb][p] + bs;
            if (resid) v += resid[(size_t)row * ldr + col];
            if (Cf) Cf[(size_t)row * ldc + col] = v;
            else    Cb[(size_t)row * ldc + col] = f2bf(v);
        }
    }
}

// ---------------------------------------------------------------------------
// RoPE from bf16 qkvb -> bf16 Q (scale 0.125 folded) and K, layout [h][n][64].
// qkvb row layout per n: h*192 + d*3 + {0:q,1:k,2:v}.
// ---------------------------------------------------------------------------
__global__ __launch_bounds__(256) void rope_qk(
    const u16* __restrict__ qkvb, const float* __restrict__ enc,
    unsigned* __restrict__ Qb, unsigned* __restrict__ Kb)
{
    const int gid = blockIdx.x * 256 + threadIdx.x;   // NH*NTOK*32
    const int h   = gid >> 17;
    const int rem = gid & (NTOK * 32 - 1);
    const int n   = rem >> 5;
    const int p   = rem & 31;
    const int d0  = p * 2;

    const u16* base = qkvb + (size_t)n * 768 + h * 192 + d0 * 3;
    const float q0v = bf2f(base[0]), k0 = bf2f(base[1]);
    const float q1  = bf2f(base[3]), k1 = bf2f(base[4]);

    float2 c01 = *(const float2*)(enc + (size_t)n * 64 + d0);
    float2 s01 = *(const float2*)(enc + (size_t)NTOK * 64 + (size_t)n * 64 + d0);

    const float qo0 = (q0v * c01.x - q1 * s01.x) * 0.125f;
    const float qo1 = (q1 * c01.y + q0v * s01.y) * 0.125f;
    const float ko0 = k0 * c01.x - k1 * s01.x;
    const float ko1 = k1 * c01.y + k0 * s01.y;

    const size_t oidx = ((size_t)(h * NTOK + n) << 5) + p;  // uint (2-elem) index
    Qb[oidx] = (unsigned)f2bf(qo0) | ((unsigned)f2bf(qo1) << 16);
    Kb[oidx] = (unsigned)f2bf(ko0) | ((unsigned)f2bf(ko1) << 16);
}

// ---------------------------------------------------------------------------
// V (bf16 slot of qkvb) -> bf16 transposed Vt[h][d][key].
// ---------------------------------------------------------------------------
__global__ __launch_bounds__(256) void v_transpose(
    const u16* __restrict__ qkvb, u16* __restrict__ Vt)
{
    const int h  = blockIdx.x >> 6;
    const int nt = blockIdx.x & 63;
    const int t  = threadIdx.x;
    const int d  = t & 63;
    const int nc = t >> 6;   // 0..3

    __align__(16) u16 us[16];
    #pragma unroll
    for (int i = 0; i < 16; ++i) {
        const int n = nt * 64 + nc * 16 + i;
        us[i] = qkvb[(size_t)n * 768 + h * 192 + d * 3 + 2];
    }
    u16* dst = Vt + ((size_t)(h * 64 + d) << 12) + nt * 64 + nc * 16;
    *(uint4*)(dst)     = *(uint4*)(us);
    *(uint4*)(dst + 8) = *(uint4*)(us + 8);
}

// ---------------------------------------------------------------------------
// Flash attention, bf16 MFMA, 8 waves (512 thr): wave = (wq, wk),
// wq in {0,1} = q-half (32 rows), wk in {0..3} = key-quarter (1024 keys).
// 2048 waves total -> 2 waves/SIMD (was 1). Per-wave P-tile 4KB in LDS
// (16B-slot XOR swizzle). Cross-wk online-softmax merge via LDS, then
// bf16 ctx output.
// ---------------------------------------------------------------------------
__global__ __launch_bounds__(512, 2) void flash_attn_mfma8(
    const u16* __restrict__ Qb, const u16* __restrict__ Kb,
    const u16* __restrict__ Vt, u16* __restrict__ ctxb)
{
    __shared__ char  Plds[8 * 4096];
    __shared__ float Obuf[64 * 64];
    __shared__ float Mbuf[64], Lbuf[64];

    const int t  = threadIdx.x;
    const int w  = t >> 6;
    const int l  = t & 63;
    const int lg = l >> 4, li = l & 15;
    const int wq = w >> 2, wk = w & 3;
    const int h  = blockIdx.y;
    const int q0 = blockIdx.x * 64;

    char* Pw = Plds + w * 4096;

    // Q fragments: rows q0 + wq*32 + Mb*16 + li, d = kh*32 + lg*8 + {0..7}
    bf16x8 QA[2][2];
    #pragma unroll
    for (int Mb = 0; Mb < 2; ++Mb)
        #pragma unroll
        for (int kh = 0; kh < 2; ++kh)
            QA[Mb][kh] = *(const bf16x8*)(Qb +
                ((size_t)(h * NTOK + q0 + wq * 32 + Mb * 16 + li) << 6) + kh * 32 + lg * 8);

    f32x4 OA[2][4];
    float mrun[2][4], lrun[2][4];
    #pragma unroll
    for (int Mb = 0; Mb < 2; ++Mb) {
        #pragma unroll
        for (int p = 0; p < 4; ++p) { mrun[Mb][p] = -1e30f; lrun[Mb][p] = 0.f; }
        #pragma unroll
        for (int db = 0; db < 4; ++db) OA[Mb][db] = (f32x4){0.f, 0.f, 0.f, 0.f};
    }

    for (int it = 0; it < 16; ++it) {
        const int kt = (wk << 10) + (it << 6);

        bf16x8 KB[4][2], VB[4][2];
        #pragma unroll
        for (int kb = 0; kb < 4; ++kb)
            #pragma unroll
            for (int kh = 0; kh < 2; ++kh)
                KB[kb][kh] = *(const bf16x8*)(Kb +
                    ((size_t)(h * NTOK + kt + kb * 16 + li) << 6) + kh * 32 + lg * 8);
        #pragma unroll
        for (int db = 0; db < 4; ++db)
            #pragma unroll
            for (int kh = 0; kh < 2; ++kh)
                VB[db][kh] = *(const bf16x8*)(Vt +
                    ((size_t)(h * 64 + db * 16 + li) << 12) + kt + kh * 32 + lg * 8);

        // ---- scores ----
        f32x4 SA[2][4];
        #pragma unroll
        for (int Mb = 0; Mb < 2; ++Mb)
            #pragma unroll
            for (int kb = 0; kb < 4; ++kb) {
                f32x4 z = (f32x4){0.f, 0.f, 0.f, 0.f};
                z = __builtin_amdgcn_mfma_f32_16x16x32_bf16(QA[Mb][0], KB[kb][0], z, 0, 0, 0);
                SA[Mb][kb] = __builtin_amdgcn_mfma_f32_16x16x32_bf16(QA[Mb][1], KB[kb][1], z, 0, 0, 0);
            }

        // ---- online softmax (rows in (lg,p); reduce over 16 li lanes) ----
        #pragma unroll
        for (int Mb = 0; Mb < 2; ++Mb)
            #pragma unroll
            for (int p = 0; p < 4; ++p) {
                float mx = fmaxf(fmaxf(SA[Mb][0][p], SA[Mb][1][p]),
                                 fmaxf(SA[Mb][2][p], SA[Mb][3][p]));
                #pragma unroll
                for (int sh = 1; sh < 16; sh <<= 1)
                    mx = fmaxf(mx, __shfl_xor(mx, sh));
                const float mo = mrun[Mb][p];
                const float mn = fmaxf(mo, mx);
                const float corr = __expf(mo - mn);
                mrun[Mb][p] = mn;
                float pv[4], ps = 0.f;
                #pragma unroll
                for (int kb = 0; kb < 4; ++kb) {
                    pv[kb] = __expf(SA[Mb][kb][p] - mn);
                    ps += pv[kb];
                }
                #pragma unroll
                for (int sh = 1; sh < 16; sh <<= 1) ps += __shfl_xor(ps, sh);
                lrun[Mb][p] = lrun[Mb][p] * corr + ps;
                #pragma unroll
                for (int db = 0; db < 4; ++db) OA[Mb][db][p] *= corr;

                const int ql = Mb * 16 + lg * 4 + p;   // 0..31
                #pragma unroll
                for (int kb = 0; kb < 4; ++kb) {
                    const int kl = kb * 16 + li;
                    *(u16*)(Pw + ql * 128 + ((kl * 2) ^ ((ql & 7) << 4))) = f2bf(pv[kb]);
                }
            }

        // ---- PV (per-wave in-order DS: writes above complete before reads) ----
        #pragma unroll
        for (int Mb = 0; Mb < 2; ++Mb)
            #pragma unroll
            for (int kh = 0; kh < 2; ++kh) {
                const int ql = Mb * 16 + li;
                bf16x8 PA = *(const bf16x8*)(Pw + ql * 128 +
                                ((kh * 64 + lg * 16) ^ ((ql & 7) << 4)));
                #pragma unroll
                for (int db = 0; db < 4; ++db)
                    OA[Mb][db] = __builtin_amdgcn_mfma_f32_16x16x32_bf16(
                        PA, VB[db][kh], OA[Mb][db], 0, 0, 0);
            }
    }

    // ---- cross-wk online-softmax merge (wq groups work disjoint rows) ----
    if (wk == 0) {
        #pragma unroll
        for (int Mb = 0; Mb < 2; ++Mb)
            #pragma unroll
            for (int p = 0; p < 4; ++p) {
                const int q = wq * 32 + Mb * 16 + lg * 4 + p;
                #pragma unroll
                for (int db = 0; db < 4; ++db)
                    Obuf[q * 64 + db * 16 + li] = OA[Mb][db][p];
                if (li == 0) { Mbuf[q] = mrun[Mb][p]; Lbuf[q] = lrun[Mb][p]; }
            }
    }
    #pragma unroll
    for (int wv = 1; wv < 4; ++wv) {
        __syncthreads();
        if (wk == wv) {
            #pragma unroll
            for (int Mb = 0; Mb < 2; ++Mb)
                #pragma unroll
                for (int p = 0; p < 4; ++p) {
                    const int q = wq * 32 + Mb * 16 + lg * 4 + p;
                    const float Mo = Mbuf[q], Lo = Lbuf[q];
                    const float mn = fmaxf(Mo, mrun[Mb][p]);
                    const float a  = __expf(Mo - mn);
                    const float b  = __expf(mrun[Mb][p] - mn);
                    #pragma unroll
                    for (int db = 0; db < 4; ++db) {
                        const int idx = q * 64 + db * 16 + li;
                        Obuf[idx] = Obuf[idx] * a + OA[Mb][db][p] * b;
                    }
                    if (li == 0) { Mbuf[q] = mn; Lbuf[q] = Lo * a + lrun[Mb][p] * b; }
                }
        }
    }
    __syncthreads();

    // ---- write ctx bf16 (N, E): ctxb[q0+q][h*64+d] ----
    {
        const int q = t >> 3, dc = (t & 7) * 8;
        const float rl = 1.f / Lbuf[q];
        uint4 ov;
        unsigned* op = (unsigned*)&ov;
        #pragma unroll
        for (int i = 0; i < 8; i += 2)
            op[i >> 1] = (unsigned)f2bf(Obuf[q * 64 + dc + i] * rl) |
                         ((unsigned)f2bf(Obuf[q * 64 + dc + i + 1] * rl) << 16);
        *(uint4*)(ctxb + (size_t)(q0 + q) * EMB + h * 64 + dc) = ov;
    }
}

// ---------------------------------------------------------------------------
// Row LayerNorm(512) + exact GeLU; fp32 in, bf16 out.
// ---------------------------------------------------------------------------
__global__ __launch_bounds__(256) void ln_gelu(
    const float* __restrict__ h1, const float* __restrict__ g,
    const float* __restrict__ b, u16* __restrict__ h2b)
{
    __shared__ float red[8];
    const int row = blockIdx.x, t = threadIdx.x;
    const float v0 = h1[(size_t)row * 512 + t];
    const float v1 = h1[(size_t)row * 512 + 256 + t];

    float s = v0 + v1;
    #pragma unroll
    for (int w = 1; w < 64; w <<= 1) s += __shfl_xor(s, w);
    if ((t & 63) == 0) red[t >> 6] = s;
    __syncthreads();
    const float mu = (red[0] + red[1] + red[2] + red[3]) * (1.f / 512.f);

    const float d0 = v0 - mu, d1 = v1 - mu;
    float vs = d0 * d0 + d1 * d1;
    #pragma unroll
    for (int w = 1; w < 64; w <<= 1) vs += __shfl_xor(vs, w);
    if ((t & 63) == 0) red[4 + (t >> 6)] = vs;
    __syncthreads();
    const float var  = (red[4] + red[5] + red[6] + red[7]) * (1.f / 512.f);
    const float rstd = rsqrtf(var + 1e-5f);

    const float y0 = d0 * rstd * g[t] + b[t];
    const float y1 = d1 * rstd * g[t + 256] + b[t + 256];
    const float o0 = 0.5f * y0 * (1.f + erff(y0 * 0.70710678118654752f));
    const float o1 = 0.5f * y1 * (1.f + erff(y1 * 0.70710678118654752f));
    h2b[(size_t)row * 512 + t]       = f2bf(o0);
    h2b[(size_t)row * 512 + 256 + t] = f2bf(o1);
}

// ---------------------------------------------------------------------------
extern "C" void kernel_launch(void* const* d_in, const int* in_sizes, int n_in,
                              void* d_out, int out_size, void* d_ws, size_t ws_size,
                              hipStream_t stream)
{
    const float* x      = (const float*)d_in[0];
    const float* enc    = (const float*)d_in[1];
    const float* Wqkv_w = (const float*)d_in[2];
    const float* Wqkv_b = (const float*)d_in[3];
    const float* out_w  = (const float*)d_in[4];
    const float* out_b  = (const float*)d_in[5];
    const float* ffn1_w = (const float*)d_in[6];
    const float* ffn1_b = (const float*)d_in[7];
    const float* ln_g   = (const float*)d_in[8];
    const float* ln_b   = (const float*)d_in[9];
    const float* ffn2_w = (const float*)d_in[10];
    const float* ffn2_b = (const float*)d_in[11];
    float* out = (float*)d_out;
    float* ws  = (float*)d_ws;

    // workspace layout (float units), peak 6,619,136 fu = 25.9 MiB:
    //  [0)         catb  bf16 4096x512          [xcast -> FFN1]
    //  [1048576)   wb    bf16 concat weights    [w4cast -> end]
    //  [1376256)   Qb    bf16 4x4096x64         [rope -> flash]
    //  [1900544)   Kb    bf16 4x4096x64
    //  [2424832)   Vt    bf16 4x64x4096
    //  [2949120)   ctxb  bf16 4096x256          [flash -> out_proj]
    //  [3473408)   qkvb  bf16 4096x768          [gemm1 -> rope/vt]
    //  [3473408)   h1    fp32 4096x512          [FFN1 -> ln]  (reuses qkvb+)
    //  [5570560)   xb    bf16 4096x256          [xcast -> gemm1]
    //  [5570560)   h2b   bf16 4096x512          [ln -> FFN2]  (reuses xb)
    u16*   catb = (u16*)(ws);
    u16*   wb   = (u16*)(ws + 1048576);
    u16*   Qb   = (u16*)(ws + 1376256);
    u16*   Kb   = (u16*)(ws + 1900544);
    u16*   Vt   = (u16*)(ws + 2424832);
    u16*   ctxb = (u16*)(ws + 2949120);
    u16*   qkvb = (u16*)(ws + 3473408);
    float* h1   = ws + 3473408;
    u16*   xb   = (u16*)(ws + 5570560);
    u16*   h2b  = (u16*)(ws + 5570560);

    u16* Wqkvb = wb;
    u16* outwb = wb + 196608;
    u16* ffn1b = wb + 262144;
    u16* ffn2b = wb + 524288;

    // 1. casts
    w4cast<<<640, 256, 0, stream>>>((const float4*)Wqkv_w, (const float4*)out_w,
                                    (const float4*)ffn1_w, (const float4*)ffn2_w, wb);
    xcast<<<1024, 256, 0, stream>>>((const float4*)x, xb, catb);
    // 2. QKV projection: (4096,256)@(768,256)^T -> bf16 qkvb
    gemm_bf16_abt<<<dim3(12, 64), 256, 0, stream>>>(xb, Wqkvb, Wqkv_b,
                                                    nullptr, 0, nullptr, qkvb, 768, 256);
    // 3. RoPE -> Qb (x0.125), Kb
    rope_qk<<<2048, 256, 0, stream>>>(qkvb, enc, (unsigned*)Qb, (unsigned*)Kb);
    // 4. V -> Vt [h][d][key]
    v_transpose<<<256, 256, 0, stream>>>(qkvb, Vt);
    // 5. attention -> ctxb bf16
    flash_attn_mfma8<<<dim3(64, NH), 512, 0, stream>>>(Qb, Kb, Vt, ctxb);
    // 6. out_proj -> catb[:, 256:]
    gemm_bf16_abt<<<dim3(4, 64), 256, 0, stream>>>(ctxb, outwb, out_b,
                                                   nullptr, 0, nullptr, catb + 256, 512, 256);
    // 7. FFN1 -> h1 fp32
    gemm_bf16_abt<<<dim3(8, 64), 256, 0, stream>>>(catb, ffn1b, ffn1_b,
                                                   nullptr, 0, h1, nullptr, 512, 512);
    // 8. LayerNorm + GeLU -> h2b bf16
    ln_gelu<<<4096, 256, 0, stream>>>(h1, ln_g, ln_b, h2b);
    // 9. FFN2 + residual -> out fp32
    gemm_bf16_abt<<<dim3(4, 64), 256, 0, stream>>>(h2b, ffn2b, ffn2_b,
                                                   x, 256, out, nullptr, 256, 512);
}